// Round 9
// baseline (297.463 us; speedup 1.0000x reference)
//
#include <hip/hip_runtime.h>

// RGCNDirectional: out = sum_r (A[r] @ (X @ W[r]^T)) / (rowsum(A[r]) + eps)
// X:[4096,128] f32, A:[8,4096,4096] f32 (512MB), W:[8,128,128] f32.
// Round 9: ingest reduction with preserved residency. BM=128 + K-split 2:
// grid 512 x 256thr (2 blocks/CU, as R3), H ingest 512->256MB. Norms done
// via cross-block protocol: siblings atomicAdd partial rowsums + counter,
// spin till both arrive (all 512 blocks co-resident; 2-way f32 add is
// commutative -> deterministic), then scale acc and atomicAdd out.
// Pipeline = R3's proven counts: 12 VMEM ops/phase, VMW(12), 2 barriers.

#define N_NODES 4096
#define DIM     128
#define NREL    8
#define EPS_F   1e-12f
#define BMR     128              // rows per block
#define BK      64
#define KSPL    2
#define PHASES  32               // (4096/KSPL)/BK
#define NKT     64
#define TILE_SHORTS (DIM * BK)   // 8192 shorts = 16 KB per H tile

typedef __attribute__((ext_vector_type(4))) float f32x4;
typedef __attribute__((ext_vector_type(8))) short bf16x8;

__device__ __forceinline__ unsigned short f2bf(float f) {
  unsigned u = __float_as_uint(f);
  return (unsigned short)((u + 0x7fffu + ((u >> 16) & 1u)) >> 16);   // RNE
}

__device__ __forceinline__ bf16x8 cvt8(const float* p) {
  f32x4 lo = *reinterpret_cast<const f32x4*>(p);
  f32x4 hi = *reinterpret_cast<const f32x4*>(p + 4);
  bf16x8 o;
#pragma unroll
  for (int j = 0; j < 4; ++j) { o[j] = (short)f2bf(lo[j]); o[j + 4] = (short)f2bf(hi[j]); }
  return o;
}

__device__ __forceinline__ void gload_lds16(const void* g, void* l) {
  __builtin_amdgcn_global_load_lds((const __attribute__((address_space(1))) void*)g,
                                   (__attribute__((address_space(3))) void*)l, 16, 0, 0);
}

// ---------------------------------------------------------------------------
// Kernel 1: Ht2[r][kt][ o*64 + (c ^ ((o&7)<<3)) ] = bf16( sum_d X[n][d]*W[r][o][d] )
// n = kt*64 + c. Tile-contiguous + XOR-swizzled (unchanged from R3, proven).
// ---------------------------------------------------------------------------
__global__ __launch_bounds__(256) void h_kernel(const float* __restrict__ X,
                                                const float* __restrict__ W,
                                                short* __restrict__ Ht2) {
  const int r  = blockIdx.x >> 5;
  const int n0 = (blockIdx.x & 31) * 128;
  const int lane = threadIdx.x & 63;
  const int wid  = threadIdx.x >> 6;
  const int wm = wid >> 1, wn = wid & 1;
  const int l15 = lane & 15, l4 = lane >> 4;

  const float* Wr = W + (size_t)r * DIM * DIM;
  f32x4 acc[4][4] = {};

#pragma unroll
  for (int ks = 0; ks < 4; ++ks) {
    const int k = ks * 32 + l4 * 8;
    bf16x8 a[4], b[4];
#pragma unroll
    for (int mi = 0; mi < 4; ++mi)
      a[mi] = cvt8(Wr + (size_t)(wm * 64 + mi * 16 + l15) * DIM + k);
#pragma unroll
    for (int ni = 0; ni < 4; ++ni)
      b[ni] = cvt8(X + (size_t)(n0 + wn * 64 + ni * 16 + l15) * DIM + k);
#pragma unroll
    for (int mi = 0; mi < 4; ++mi)
#pragma unroll
      for (int ni = 0; ni < 4; ++ni)
        acc[mi][ni] = __builtin_amdgcn_mfma_f32_16x16x32_bf16(a[mi], b[ni], acc[mi][ni], 0, 0, 0);
  }

#pragma unroll
  for (int mi = 0; mi < 4; ++mi)
#pragma unroll
    for (int ni = 0; ni < 4; ++ni)
#pragma unroll
      for (int i = 0; i < 4; ++i) {
        const int o = wm * 64 + mi * 16 + l4 * 4 + i;
        const int n = n0 + wn * 64 + ni * 16 + l15;
        const int kt = n >> 6, c = n & 63;
        Ht2[(size_t)(r * NKT + kt) * TILE_SHORTS + o * 64 + (c ^ ((o & 7) << 3))] =
            (short)f2bf(acc[mi][ni][i]);
      }
}

// ---------------------------------------------------------------------------
// Kernel 2: main. Block = (r, 128-row tile, K-half). 4 waves x 32 rows.
// Per phase: 4x gload_lds (next H tile) + 8x A dwordx4 (next tile, regs),
// VMW(12), BAR, 32 MFMA (2 m-frags x 8 n x 2 ks), BAR. 32 phases.
// Epilogue: partial rowsums -> norms atomics, counter spin, scale, out adds.
// ---------------------------------------------------------------------------
__global__ __launch_bounds__(256, 2) void rgcn_main(const float* __restrict__ A,
                                                    const short* __restrict__ Ht2,
                                                    float* __restrict__ out,
                                                    float* __restrict__ norms,
                                                    int* __restrict__ counters) {
  // XCD x owns relation x: 64 blocks/XCD (32 mtiles x 2 ksplit); both K-halves
  // of Ht2[r] (1MB) stay L2-resident on that XCD.
  const int logical = (blockIdx.x & 7) * 64 + (blockIdx.x >> 3);
  const int r   = logical >> 6;
  const int rem = logical & 63;
  const int mt  = rem >> 1;
  const int ksp = rem & 1;
  const int m0  = mt * BMR;
  const int cidx = r * 32 + mt;

  const int tid  = threadIdx.x;
  const int lane = tid & 63;
  const int w    = tid >> 6;             // wave owns rows m0 + w*32 .. +32
  const int l15  = lane & 15, l4 = lane >> 4;

  __shared__ __align__(128) short Hs[2][TILE_SHORTS];   // 32 KB

  const float* Ag = A + ((size_t)r * N_NODES + m0 + w * 32 + l15) * N_NODES
                      + (size_t)ksp * (N_NODES / KSPL) + l4 * 8;
  const short* Hgw = Ht2 + (size_t)(r * NKT + ksp * PHASES) * TILE_SHORTS
                        + w * 2048 + lane * 8;
  short* lds0 = &Hs[0][0] + w * 2048;
  short* lds1 = &Hs[1][0] + w * 2048;

  f32x4 acc[2][8] = {};                 // [mf][ni]
  f32x4 a0[2][2][2], a1[2][2][2];       // [ks][mf][lo/hi]
  float rs[2] = {0.f, 0.f};             // rowsum partials (rows l15+mf*16)

  auto stageH = [&](short* ldsb, int t) {
    const short* g = Hgw + (size_t)t * TILE_SHORTS;
#pragma unroll
    for (int j = 0; j < 4; ++j)
      gload_lds16(g + j * 512, ldsb + j * 512);
  };
  auto loadA = [&](f32x4 (&d)[2][2][2], int t) {
    const float* p = Ag + (size_t)t * BK;
#pragma unroll
    for (int ks = 0; ks < 2; ++ks)
#pragma unroll
      for (int mf = 0; mf < 2; ++mf) {
        const float* q = p + (size_t)mf * 16 * N_NODES + ks * 32;
        d[ks][mf][0] = *reinterpret_cast<const f32x4*>(q);
        d[ks][mf][1] = *reinterpret_cast<const f32x4*>(q + 4);
      }
  };

  const char* hbase = (const char*)&Hs[0][0] + (size_t)l15 * 128;
  const int swz = (l15 & 7) << 4;
  auto compute = [&](int buf, f32x4 (&av)[2][2][2]) {
    const char* hb = hbase + (size_t)buf * (TILE_SHORTS * 2);
#pragma unroll
    for (int ks = 0; ks < 2; ++ks) {
      bf16x8 ab[2];
#pragma unroll
      for (int mf = 0; mf < 2; ++mf)
#pragma unroll
        for (int j = 0; j < 4; ++j) {
          ab[mf][j]     = (short)f2bf(av[ks][mf][0][j]);
          ab[mf][j + 4] = (short)f2bf(av[ks][mf][1][j]);
          rs[mf] += av[ks][mf][0][j] + av[ks][mf][1][j];
        }
      const int cb = ks * 64 + l4 * 16;
#pragma unroll
      for (int ni = 0; ni < 8; ++ni) {
        bf16x8 h = *reinterpret_cast<const bf16x8*>(hb + ni * 2048 + (cb ^ swz));
        acc[0][ni] = __builtin_amdgcn_mfma_f32_16x16x32_bf16(ab[0], h, acc[0][ni], 0, 0, 0);
        acc[1][ni] = __builtin_amdgcn_mfma_f32_16x16x32_bf16(ab[1], h, acc[1][ni], 0, 0, 0);
      }
    }
  };

#define VMW(N) do { __builtin_amdgcn_sched_barrier(0);                      \
    asm volatile("s_waitcnt vmcnt(" #N ")" ::: "memory");                   \
    __builtin_amdgcn_sched_barrier(0); } while (0)
#define PH(C, P, KT) do {                                                   \
    stageH(lds##P, KT); loadA(a##P, KT);                                    \
    VMW(12);                                                                \
    __builtin_amdgcn_s_barrier();                                           \
    compute(C, a##C);                                                       \
    __builtin_amdgcn_s_barrier(); } while (0)

  stageH(lds0, 0); loadA(a0, 0);
  for (int s = 0; s < 15; ++s) {         // phases 0..29: tiles 0..29
    PH(0, 1, 2 * s + 1);
    PH(1, 0, 2 * s + 2);
  }
  PH(0, 1, 31);                          // phase 30: compute tile 30, stage 31
  VMW(0);                                // phase 31
  __builtin_amdgcn_s_barrier();
  compute(1, a1);

#undef PH
#undef VMW

  // ---- cross-block norm protocol ----
#pragma unroll
  for (int mf = 0; mf < 2; ++mf) {
    float s = rs[mf];
    s += __shfl_xor(s, 16);
    s += __shfl_xor(s, 32);              // lanes sharing l15 now hold row sum
    if (l4 == 0)
      atomicAdd(&norms[r * N_NODES + m0 + w * 32 + mf * 16 + l15], s);
  }
  __threadfence();
  __syncthreads();
  if (tid == 0) {
    atomicAdd(&counters[cidx], 1);
    while (__hip_atomic_load(&counters[cidx], __ATOMIC_ACQUIRE,
                             __HIP_MEMORY_SCOPE_AGENT) < KSPL)
      __builtin_amdgcn_s_sleep(4);
  }
  __syncthreads();

  float ninv[2][4];
#pragma unroll
  for (int mf = 0; mf < 2; ++mf)
#pragma unroll
    for (int i = 0; i < 4; ++i) {
      float nv = __hip_atomic_load(
          &norms[r * N_NODES + m0 + w * 32 + mf * 16 + l4 * 4 + i],
          __ATOMIC_RELAXED, __HIP_MEMORY_SCOPE_AGENT);
      ninv[mf][i] = 1.0f / (nv + EPS_F);
    }

  float* orow = out + (size_t)(m0 + w * 32) * DIM;
#pragma unroll
  for (int mf = 0; mf < 2; ++mf)
#pragma unroll
    for (int ni = 0; ni < 8; ++ni)
#pragma unroll
      for (int i = 0; i < 4; ++i)
        atomicAdd(&orow[(size_t)(mf * 16 + l4 * 4 + i) * DIM + ni * 16 + l15],
                  acc[mf][ni][i] * ninv[mf][i]);
}

extern "C" void kernel_launch(void* const* d_in, const int* in_sizes, int n_in,
                              void* d_out, int out_size, void* d_ws, size_t ws_size,
                              hipStream_t stream) {
  const float* X = (const float*)d_in[0];
  const float* A = (const float*)d_in[1];
  const float* W = (const float*)d_in[2];
  float* out = (float*)d_out;

  char* ws = (char*)d_ws;
  short* Ht2    = (short*)ws;                         // 8 MiB
  float* norms  = (float*)(ws + (8u << 20));          // 128 KiB
  int*   counters = (int*)(ws + (8u << 20) + (128u << 10));   // 1 KiB

  hipMemsetAsync(d_out, 0, (size_t)out_size * sizeof(float), stream);
  hipMemsetAsync(ws + (8u << 20), 0, (128u << 10) + 1024, stream);
  hipLaunchKernelGGL(h_kernel, dim3(NREL * (N_NODES / 128)), dim3(256), 0, stream, X, W, Ht2);
  hipLaunchKernelGGL(rgcn_main, dim3(NREL * (N_NODES / BMR) * KSPL), dim3(256), 0, stream,
                     A, Ht2, out, norms, counters);
}

// Round 10
// 194.409 us; speedup vs baseline: 1.5301x; 1.5301x over previous
//
#include <hip/hip_runtime.h>

// RGCNDirectional: out = sum_r (A[r] @ (X @ W[r]^T)) / (rowsum(A[r]) + eps)
// X:[4096,128] f32, A:[8,4096,4096] f32 (512MB), W:[8,128,128] f32.
// Round 10: TLP doubling on the proven R3 frame. Evidence: all variants show
// Occupancy ~20%, HBM/VALU/MFMA all idle -> concurrency-starved at 8 waves/CU.
// Change: 512-thread blocks, 8 waves = 4 m-quarters x 2 o-halves (16 rows x
// 64 cols each). Grid 512 (2 blocks/CU) unchanged -> 16 waves/CU, 4/SIMD.
// Byte volume identical: H staged cooperatively (2 gload_lds/wave), A dup
// loads within a block are L1/L2 hits. VMW(6)/phase, 2 barriers (R3 rules).

#define N_NODES 4096
#define DIM     128
#define NREL    8
#define EPS_F   1e-12f
#define BM      64
#define BK      64
#define NKT     (N_NODES / BK)   // 64
#define TILE_SHORTS (DIM * BK)   // 8192 shorts = 16 KB per H tile

typedef __attribute__((ext_vector_type(4))) float f32x4;
typedef __attribute__((ext_vector_type(8))) short bf16x8;

__device__ __forceinline__ unsigned short f2bf(float f) {
  unsigned u = __float_as_uint(f);
  return (unsigned short)((u + 0x7fffu + ((u >> 16) & 1u)) >> 16);   // RNE
}

__device__ __forceinline__ bf16x8 cvt8(const float* p) {
  f32x4 lo = *reinterpret_cast<const f32x4*>(p);
  f32x4 hi = *reinterpret_cast<const f32x4*>(p + 4);
  bf16x8 o;
#pragma unroll
  for (int j = 0; j < 4; ++j) { o[j] = (short)f2bf(lo[j]); o[j + 4] = (short)f2bf(hi[j]); }
  return o;
}

__device__ __forceinline__ void gload_lds16(const void* g, void* l) {
  __builtin_amdgcn_global_load_lds((const __attribute__((address_space(1))) void*)g,
                                   (__attribute__((address_space(3))) void*)l, 16, 0, 0);
}

// ---------------------------------------------------------------------------
// Kernel 1: Ht2[r][kt][ o*64 + (c ^ ((o&7)<<3)) ] = bf16( sum_d X[n][d]*W[r][o][d] )
// n = kt*64 + c. Tile-contiguous + XOR-swizzled (unchanged, proven).
// ---------------------------------------------------------------------------
__global__ __launch_bounds__(256) void h_kernel(const float* __restrict__ X,
                                                const float* __restrict__ W,
                                                short* __restrict__ Ht2) {
  const int r  = blockIdx.x >> 5;
  const int n0 = (blockIdx.x & 31) * 128;
  const int lane = threadIdx.x & 63;
  const int wid  = threadIdx.x >> 6;
  const int wm = wid >> 1, wn = wid & 1;
  const int l15 = lane & 15, l4 = lane >> 4;

  const float* Wr = W + (size_t)r * DIM * DIM;
  f32x4 acc[4][4] = {};

#pragma unroll
  for (int ks = 0; ks < 4; ++ks) {
    const int k = ks * 32 + l4 * 8;
    bf16x8 a[4], b[4];
#pragma unroll
    for (int mi = 0; mi < 4; ++mi)
      a[mi] = cvt8(Wr + (size_t)(wm * 64 + mi * 16 + l15) * DIM + k);
#pragma unroll
    for (int ni = 0; ni < 4; ++ni)
      b[ni] = cvt8(X + (size_t)(n0 + wn * 64 + ni * 16 + l15) * DIM + k);
#pragma unroll
    for (int mi = 0; mi < 4; ++mi)
#pragma unroll
      for (int ni = 0; ni < 4; ++ni)
        acc[mi][ni] = __builtin_amdgcn_mfma_f32_16x16x32_bf16(a[mi], b[ni], acc[mi][ni], 0, 0, 0);
  }

#pragma unroll
  for (int mi = 0; mi < 4; ++mi)
#pragma unroll
    for (int ni = 0; ni < 4; ++ni)
#pragma unroll
      for (int i = 0; i < 4; ++i) {
        const int o = wm * 64 + mi * 16 + l4 * 4 + i;
        const int n = n0 + wn * 64 + ni * 16 + l15;
        const int kt = n >> 6, c = n & 63;
        Ht2[(size_t)(r * NKT + kt) * TILE_SHORTS + o * 64 + (c ^ ((o & 7) << 3))] =
            (short)f2bf(acc[mi][ni][i]);
      }
}

// ---------------------------------------------------------------------------
// Kernel 2: main. Block = (relation r, 64 out rows), 512 threads / 8 waves.
// Wave w: wm=w&3 owns rows m0+wm*16..+16; wo=w>>2 owns cols wo*64..+64.
// Per phase per wave: 2x gload_lds (H tile slice) + 4x A dwordx4 (next tile,
// regs; wo-pair duplicates hit L1), VMW(6), BAR, 8 MFMA, BAR.
// ---------------------------------------------------------------------------
__global__ __launch_bounds__(512, 4) void rgcn_main(const float* __restrict__ A,
                                                    const short* __restrict__ Ht2,
                                                    float* __restrict__ out) {
  // XCD swizzle (512 = 8 XCD * 64): XCD x owns relation x -> Ht2[r] (1MB)
  // stays L2-resident per XCD.
  const int logical = (blockIdx.x & 7) * 64 + (blockIdx.x >> 3);
  const int r  = logical >> 6;
  const int m0 = (logical & 63) * BM;

  const int tid  = threadIdx.x;
  const int lane = tid & 63;
  const int w    = tid >> 6;
  const int wm   = w & 3;        // m-quarter
  const int wo   = w >> 2;       // o-half
  const int l15  = lane & 15, l4 = lane >> 4;

  __shared__ __align__(128) short Hs[2][TILE_SHORTS];   // 32 KB

  const float* Arow = A + ((size_t)r * N_NODES + m0 + wm * 16 + l15) * N_NODES + l4 * 8;
  const short* Hgw  = Ht2 + (size_t)r * NKT * TILE_SHORTS + w * 1024 + lane * 8;
  short* lds0 = &Hs[0][0] + w * 1024;   // wave-uniform staging bases (2 KB/wave)
  short* lds1 = &Hs[1][0] + w * 1024;

  f32x4 acc[4] = {};            // ni = 0..3 within this wave's o-half
  f32x4 a0[2][2], a1[2][2];     // [ks][lo/hi]: 8 f32 at k = ks*32 + l4*8
  float rs = 0.f;

  auto stage = [&](short* ldsb, int kt) {
    const short* g = Hgw + (size_t)kt * TILE_SHORTS;
    gload_lds16(g, ldsb);
    gload_lds16(g + 512, ldsb + 512);
  };
  auto loadA = [&](f32x4 (&d)[2][2], int kt) {
    const float* p = Arow + kt * BK;
    d[0][0] = *reinterpret_cast<const f32x4*>(p);
    d[0][1] = *reinterpret_cast<const f32x4*>(p + 4);
    d[1][0] = *reinterpret_cast<const f32x4*>(p + 32);
    d[1][1] = *reinterpret_cast<const f32x4*>(p + 36);
  };

  const char* hbase = (const char*)&Hs[0][0] + (size_t)l15 * 128 + (size_t)wo * 4 * 2048;
  const int swz = (l15 & 7) << 4;
  auto compute = [&](int buf, f32x4 (&av)[2][2]) {
    const char* hb = hbase + (size_t)buf * (TILE_SHORTS * 2);
#pragma unroll
    for (int ks = 0; ks < 2; ++ks) {
      bf16x8 ab;
#pragma unroll
      for (int j = 0; j < 4; ++j) {
        ab[j]     = (short)f2bf(av[ks][0][j]);
        ab[j + 4] = (short)f2bf(av[ks][1][j]);
        rs += av[ks][0][j] + av[ks][1][j];
      }
      const int cb = ks * 64 + l4 * 16;
#pragma unroll
      for (int ni = 0; ni < 4; ++ni) {
        bf16x8 h = *reinterpret_cast<const bf16x8*>(hb + ni * 2048 + (cb ^ swz));
        acc[ni] = __builtin_amdgcn_mfma_f32_16x16x32_bf16(ab, h, acc[ni], 0, 0, 0);
      }
    }
  };

#define VMW(N) do { __builtin_amdgcn_sched_barrier(0);                      \
    asm volatile("s_waitcnt vmcnt(" #N ")" ::: "memory");                   \
    __builtin_amdgcn_sched_barrier(0); } while (0)

  // phase p: issue tile p+1 (6 VMEM ops), wait tile p landed (vmcnt(6)),
  // barrier, compute tile p. Two barriers per phase (proven R3 discipline).
#define PH(C, P, KT) do {                                                   \
    stage(lds##P, KT); loadA(a##P, KT);                                     \
    VMW(6);                                                                 \
    __builtin_amdgcn_s_barrier();                                           \
    compute(C, a##C);                                                       \
    __builtin_amdgcn_s_barrier(); } while (0)

  // prologue: tile 0, full drain
  stage(lds0, 0); loadA(a0, 0);
  VMW(0);
  __builtin_amdgcn_s_barrier();

  for (int t = 0; t < NKT - 2; t += 2) {   // phases 0..61
    PH(0, 1, t + 1);
    PH(1, 0, t + 2);
  }
  PH(0, 1, 63);                            // phase 62
  VMW(0); __builtin_amdgcn_s_barrier();    // phase 63
  compute(1, a1);

#undef PH
#undef VMW

  // rowsum reduce: lanes {l15, l15+16, l15+32, l15+48} hold partials of row
  // l15 (identical in both wo-halves; each wave computes its own copy)
  rs += __shfl_xor(rs, 16);
  rs += __shfl_xor(rs, 32);
  float ninv[4];
#pragma unroll
  for (int i = 0; i < 4; ++i)
    ninv[i] = 1.0f / (__shfl(rs, l4 * 4 + i) + EPS_F);  // source lane's l15 == row

  float* orow = out + (size_t)(m0 + wm * 16) * DIM + wo * 64;
#pragma unroll
  for (int ni = 0; ni < 4; ++ni)
#pragma unroll
    for (int i = 0; i < 4; ++i)
      atomicAdd(&orow[(size_t)(l4 * 4 + i) * DIM + ni * 16 + l15], acc[ni][i] * ninv[i]);
}

extern "C" void kernel_launch(void* const* d_in, const int* in_sizes, int n_in,
                              void* d_out, int out_size, void* d_ws, size_t ws_size,
                              hipStream_t stream) {
  const float* X = (const float*)d_in[0];
  const float* A = (const float*)d_in[1];
  const float* W = (const float*)d_in[2];
  float* out = (float*)d_out;
  short* Ht2 = (short*)d_ws;   // 8 r * 64 kt * 16 KB = 8 MB

  hipMemsetAsync(d_out, 0, (size_t)out_size * sizeof(float), stream);
  hipLaunchKernelGGL(h_kernel, dim3(NREL * (N_NODES / 128)), dim3(256), 0, stream, X, W, Ht2);
  hipLaunchKernelGGL(rgcn_main, dim3(NREL * (N_NODES / BM)), dim3(512), 0, stream, A, Ht2, out);
}